// Round 21
// baseline (475.336 us; speedup 1.0000x reference)
//
#include <hip/hip_runtime.h>
#include <math.h>

#define NPG 28
#define EPG 64
#define NB  256
#define NG  512
#define NN  14336
#define NE  32768
#define TEMPINV 10.0f
#define SINK_ITERS 20
#define CW 0.9f

typedef unsigned int uint;
typedef unsigned short ushort;
typedef __attribute__((ext_vector_type(8))) __bf16 bf16x8;
typedef __attribute__((ext_vector_type(4))) float f32x4;

__device__ __forceinline__ ushort f2bf(float x) {
    uint u = __float_as_uint(x);
    u += 0x7fffu + ((u >> 16) & 1u);
    return (ushort)(u >> 16);
}
__device__ __forceinline__ uint f2bf2(float lo, float hi) {
    return (uint)f2bf(lo) | ((uint)f2bf(hi) << 16);
}
__device__ __forceinline__ float bflo(uint w) { return __uint_as_float(w << 16); }
__device__ __forceinline__ float bfhi(uint w) { return __uint_as_float(w & 0xffff0000u); }
__device__ __forceinline__ uint relu_sum_pk(uint w1, uint w2, uint w3) {
    float lo = fmaxf(bflo(w1) + bflo(w2) + bflo(w3), 0.f);
    float hi = fmaxf(bfhi(w1) + bfhi(w2) + bfhi(w3), 0.f);
    return f2bf2(lo, hi);
}
__device__ __forceinline__ uint4 pack_f32x8(const float* src) {
    const float4 f0 = *(const float4*)src;
    const float4 f1 = *(const float4*)(src + 4);
    uint4 o;
    o.x = f2bf2(f0.x, f0.y);
    o.y = f2bf2(f0.z, f0.w);
    o.z = f2bf2(f1.x, f1.y);
    o.w = f2bf2(f1.z, f1.w);
    return o;
}
__device__ __forceinline__ f32x4 mfma16(bf16x8 a, bf16x8 b, f32x4 c) {
    return __builtin_amdgcn_mfma_f32_16x16x32_bf16(a, b, c, 0, 0, 0);
}

// ---------------------------------------------------------------------------
// Mega-fused GNN kernel (round-12/14 verified structure, UNCHANGED)
// ---------------------------------------------------------------------------
__global__ __launch_bounds__(512) void gnn_fused(
    const float* __restrict__ nf, const float* __restrict__ ef,
    const ushort* __restrict__ encL, const float* __restrict__ enc_nb,
    const ushort* __restrict__ WcombL, const float* __restrict__ bcomb,
    const ushort* __restrict__ WhpL,
    const ushort* __restrict__ W2fL, const ushort* __restrict__ W2rL,
    const float* __restrict__ b2f, const float* __restrict__ b2r,
    const ushort* __restrict__ UW1T, const float* __restrict__ ub1,
    const ushort* __restrict__ UW2T, const float* __restrict__ ub2,
    const int* __restrict__ from_idx, const int* __restrict__ to_idx,
    float* __restrict__ h, float* __restrict__ EM)
{
    __shared__ ushort HPs[NPG * 520];
    __shared__ ushort ECs[2 * 8 * 2048];
    __shared__ float acc_s[NPG * 132];
    __shared__ float hs[NPG * 132];
    __shared__ int fl[64], tl[64];
    const int g = blockIdx.x;
    const int tid = threadIdx.x;
    const int w = tid >> 6, lane = tid & 63;
    const int li = lane & 15, quad = lane >> 4;
    const int wm = w >> 1, wn = w & 1;
    ushort* hid = &HPs[0];

    if (tid < 64) {
        fl[tid] = from_idx[g * 64 + tid] - g * NPG;
        tl[tid] = to_idx[g * 64 + tid] - g * NPG;
    }

    {   // node encoder
        uint4 anf[2];
#pragma unroll
        for (int mi = 0; mi < 2; ++mi) {
            const int row = mi * 16 + li;
            const int rr = (row < NPG) ? row : 0;
            const float4 f0 = *(const float4*)(nf + ((size_t)g * NPG + rr) * 32 + quad * 8);
            const float4 f1 = *(const float4*)(nf + ((size_t)g * NPG + rr) * 32 + quad * 8 + 4);
            uint4 o;
            o.x = f2bf2(f0.x, f0.y); o.y = f2bf2(f0.z, f0.w);
            o.z = f2bf2(f1.x, f1.y); o.w = f2bf2(f1.z, f1.w);
            anf[mi] = o;
        }
        const int col = w * 16 + li;
        const bf16x8 b = __builtin_bit_cast(bf16x8,
            *(const uint4*)(encL + (size_t)col * 32 + quad * 8));
        f32x4 c0 = mfma16(__builtin_bit_cast(bf16x8, anf[0]), b, f32x4{0.f, 0.f, 0.f, 0.f});
        f32x4 c1 = mfma16(__builtin_bit_cast(bf16x8, anf[1]), b, f32x4{0.f, 0.f, 0.f, 0.f});
        const float bv = enc_nb[col];
#pragma unroll
        for (int r = 0; r < 4; ++r) {
            const int r0 = quad * 4 + r;
            hs[r0 * 132 + col] = c0[r] + bv;
            const int r1 = 16 + quad * 4 + r;
            if (r1 < NPG) hs[r1 * 132 + col] = c1[r] + bv;
        }
    }
    {   // EC in LDS
        uint4 aef[4];
#pragma unroll
        for (int mi = 0; mi < 4; ++mi) {
            const int e = mi * 16 + li;
            const float4 f0 = *(const float4*)(ef + ((size_t)g * 64 + e) * 32 + quad * 8);
            const float4 f1 = *(const float4*)(ef + ((size_t)g * 64 + e) * 32 + quad * 8 + 4);
            uint4 o;
            o.x = f2bf2(f0.x, f0.y); o.y = f2bf2(f0.z, f0.w);
            o.z = f2bf2(f1.x, f1.y); o.w = f2bf2(f1.z, f1.w);
            aef[mi] = o;
        }
#pragma unroll
        for (int ni = 0; ni < 4; ++ni) {
            const int col = w * 64 + ni * 16 + li;
            const bf16x8 b = __builtin_bit_cast(bf16x8,
                *(const uint4*)(WcombL + (size_t)col * 32 + quad * 8));
            const float bv = bcomb[col];
            const int pp = col >> 8, kbl = (col >> 5) & 7, j = col & 31;
#pragma unroll
            for (int mi = 0; mi < 4; ++mi) {
                f32x4 c = mfma16(__builtin_bit_cast(bf16x8, aef[mi]), b,
                                 f32x4{0.f, 0.f, 0.f, 0.f});
#pragma unroll
                for (int r = 0; r < 4; ++r) {
                    const int e = mi * 16 + quad * 4 + r;
                    ECs[pp * 16384 + kbl * 2048 + e * 32 + j] = f2bf(c[r] + bv);
                }
            }
        }
    }
    __syncthreads();

#pragma unroll 1
    for (int step = 0; step < 3; ++step) {
        uint4 ha[2][4];
#pragma unroll
        for (int mi = 0; mi < 2; ++mi) {
            const int row = mi * 16 + li;
            const int rr = (row < NPG) ? row : 0;
#pragma unroll
            for (int kb = 0; kb < 4; ++kb)
                ha[mi][kb] = pack_f32x8(&hs[rr * 132 + kb * 32 + quad * 8]);
        }
        for (int u = tid; u < NPG * 132; u += 512) acc_s[u] = 0.f;

        f32x4 acc[4];
#pragma unroll
        for (int j = 0; j < 4; ++j) acc[j] = f32x4{0.f, 0.f, 0.f, 0.f};

#pragma unroll 1
        for (int p = 0; p < 2; ++p) {
            {
                const int colw = w * 64;
#pragma unroll
                for (int ni = 0; ni < 4; ++ni) {
                    const int col = colw + ni * 16 + li;
                    const ushort* pb = WhpL + (size_t)(p * 512 + col) * 32 + quad * 8;
                    f32x4 c0 = f32x4{0.f, 0.f, 0.f, 0.f};
                    f32x4 c1 = f32x4{0.f, 0.f, 0.f, 0.f};
#pragma unroll
                    for (int kb = 0; kb < 4; ++kb) {
                        const bf16x8 b = __builtin_bit_cast(bf16x8,
                            *(const uint4*)(pb + (size_t)kb * 32768));
                        c0 = mfma16(__builtin_bit_cast(bf16x8, ha[0][kb]), b, c0);
                        c1 = mfma16(__builtin_bit_cast(bf16x8, ha[1][kb]), b, c1);
                    }
#pragma unroll
                    for (int r = 0; r < 4; ++r) {
                        const int r0 = quad * 4 + r;
                        HPs[r0 * 520 + col] = f2bf(c0[r]);
                        const int r1 = 16 + quad * 4 + r;
                        if (r1 < NPG) HPs[r1 * 520 + col] = f2bf(c1[r]);
                    }
                }
            }
            __syncthreads();

            if (p == 1) {
#pragma unroll
                for (int j = 0; j < 4; ++j) acc[j] = f32x4{0.f, 0.f, 0.f, 0.f};
            }
            const int e = wm * 16 + li;
            const int i1 = p ? tl[e] : fl[e];
            const int i2 = p ? fl[e] : tl[e];
            const int ad1 = i1 * 520 + quad * 8;
            const int ad2 = i2 * 520 + 256 + quad * 8;
            const int ade = p * 16384 + e * 32 + quad * 8;
            const ushort* W2L = p ? W2rL : W2fL;
            const int n0 = wn * 64;
            const ushort* pb[4];
#pragma unroll
            for (int ni = 0; ni < 4; ++ni)
                pb[ni] = W2L + (size_t)(n0 + ni * 16 + li) * 32 + quad * 8;
#pragma unroll
            for (int kb = 0; kb < 8; ++kb) {
                const uint4 u1 = *(const uint4*)&HPs[ad1 + kb * 32];
                const uint4 u2 = *(const uint4*)&HPs[ad2 + kb * 32];
                const uint4 ue = *(const uint4*)&ECs[ade + kb * 2048];
                uint4 o;
                o.x = relu_sum_pk(u1.x, u2.x, ue.x);
                o.y = relu_sum_pk(u1.y, u2.y, ue.y);
                o.z = relu_sum_pk(u1.z, u2.z, ue.z);
                o.w = relu_sum_pk(u1.w, u2.w, ue.w);
                const bf16x8 a = __builtin_bit_cast(bf16x8, o);
#pragma unroll
                for (int ni = 0; ni < 4; ++ni) {
                    const bf16x8 b = __builtin_bit_cast(bf16x8,
                        *(const uint4*)(pb[ni] + (size_t)kb * 4096));
                    acc[ni] = mfma16(a, b, acc[ni]);
                }
            }
            {
                const int* targ = p ? fl : tl;
                const float* bias = p ? b2r : b2f;
                float bv[4];
#pragma unroll
                for (int ni = 0; ni < 4; ++ni) bv[ni] = bias[n0 + ni * 16 + li];
#pragma unroll
                for (int r = 0; r < 4; ++r) {
                    const int loc = targ[wm * 16 + quad * 4 + r];
#pragma unroll
                    for (int ni = 0; ni < 4; ++ni)
                        atomicAdd(&acc_s[loc * 132 + n0 + ni * 16 + li],
                                  acc[ni][r] + bv[ni]);
                }
            }
            __syncthreads();
        }

        {   // upd1
            const int n0u = w * 32;
            f32x4 ua[2][2];
#pragma unroll
            for (int mi = 0; mi < 2; ++mi)
#pragma unroll
                for (int ni = 0; ni < 2; ++ni) ua[mi][ni] = f32x4{0.f, 0.f, 0.f, 0.f};
            const ushort* pb0 = UW1T + (size_t)(n0u + li) * 256 + quad * 8;
            const ushort* pb1 = UW1T + (size_t)(n0u + 16 + li) * 256 + quad * 8;
#pragma unroll
            for (int kb = 0; kb < 8; ++kb) {
                bf16x8 a[2];
                if (kb < 4) {
#pragma unroll
                    for (int mi = 0; mi < 2; ++mi) {
                        const int row = mi * 16 + li;
                        const int rr = (row < NPG) ? row : 0;
                        a[mi] = __builtin_bit_cast(bf16x8,
                            pack_f32x8(&acc_s[rr * 132 + kb * 32 + quad * 8]));
                    }
                } else {
                    a[0] = __builtin_bit_cast(bf16x8, ha[0][kb - 4]);
                    a[1] = __builtin_bit_cast(bf16x8, ha[1][kb - 4]);
                }
                const bf16x8 b0 = __builtin_bit_cast(bf16x8, *(const uint4*)(pb0 + kb * 32));
                const bf16x8 b1 = __builtin_bit_cast(bf16x8, *(const uint4*)(pb1 + kb * 32));
#pragma unroll
                for (int mi = 0; mi < 2; ++mi) {
                    ua[mi][0] = mfma16(a[mi], b0, ua[mi][0]);
                    ua[mi][1] = mfma16(a[mi], b1, ua[mi][1]);
                }
            }
            const float bv0 = ub1[n0u + li], bv1 = ub1[n0u + 16 + li];
#pragma unroll
            for (int mi = 0; mi < 2; ++mi)
#pragma unroll
                for (int r = 0; r < 4; ++r) {
                    const int row = mi * 16 + quad * 4 + r;
                    if (row < NPG) {
                        hid[row * 264 + n0u + li] = f2bf(fmaxf(ua[mi][0][r] + bv0, 0.f));
                        hid[row * 264 + n0u + 16 + li] = f2bf(fmaxf(ua[mi][1][r] + bv1, 0.f));
                    }
                }
        }
        __syncthreads();
        {   // upd2
            const int n0u = w * 16;
            f32x4 ua[2];
            ua[0] = f32x4{0.f, 0.f, 0.f, 0.f};
            ua[1] = f32x4{0.f, 0.f, 0.f, 0.f};
            const ushort* pb0 = UW2T + (size_t)(n0u + li) * 256 + quad * 8;
#pragma unroll
            for (int kb = 0; kb < 8; ++kb) {
                bf16x8 a[2];
#pragma unroll
                for (int mi = 0; mi < 2; ++mi) {
                    const int row = mi * 16 + li;
                    const int rr = (row < NPG) ? row : 0;
                    a[mi] = __builtin_bit_cast(bf16x8,
                        *(const uint4*)&hid[rr * 264 + kb * 32 + quad * 8]);
                }
                const bf16x8 b0 = __builtin_bit_cast(bf16x8, *(const uint4*)(pb0 + kb * 32));
                ua[0] = mfma16(a[0], b0, ua[0]);
                ua[1] = mfma16(a[1], b0, ua[1]);
            }
            const float bv = ub2[n0u + li];
#pragma unroll
            for (int mi = 0; mi < 2; ++mi)
#pragma unroll
                for (int r = 0; r < 4; ++r) {
                    const int row = mi * 16 + quad * 4 + r;
                    if (row < NPG)
                        hs[row * 132 + n0u + li] += ua[mi][r] + bv;
                }
        }
        __syncthreads();
    }

    // final messages (EMIT)
    {
        uint4 ha[2][4];
#pragma unroll
        for (int mi = 0; mi < 2; ++mi) {
            const int row = mi * 16 + li;
            const int rr = (row < NPG) ? row : 0;
#pragma unroll
            for (int kb = 0; kb < 4; ++kb)
                ha[mi][kb] = pack_f32x8(&hs[rr * 132 + kb * 32 + quad * 8]);
        }
        f32x4 acc[4];
#pragma unroll
        for (int j = 0; j < 4; ++j) acc[j] = f32x4{0.f, 0.f, 0.f, 0.f};
        const int n0 = wn * 64;
#pragma unroll 1
        for (int p = 0; p < 2; ++p) {
            {
                const int colw = w * 64;
#pragma unroll
                for (int ni = 0; ni < 4; ++ni) {
                    const int col = colw + ni * 16 + li;
                    const ushort* pb = WhpL + (size_t)(p * 512 + col) * 32 + quad * 8;
                    f32x4 c0 = f32x4{0.f, 0.f, 0.f, 0.f};
                    f32x4 c1 = f32x4{0.f, 0.f, 0.f, 0.f};
#pragma unroll
                    for (int kb = 0; kb < 4; ++kb) {
                        const bf16x8 b = __builtin_bit_cast(bf16x8,
                            *(const uint4*)(pb + (size_t)kb * 32768));
                        c0 = mfma16(__builtin_bit_cast(bf16x8, ha[0][kb]), b, c0);
                        c1 = mfma16(__builtin_bit_cast(bf16x8, ha[1][kb]), b, c1);
                    }
#pragma unroll
                    for (int r = 0; r < 4; ++r) {
                        const int r0 = quad * 4 + r;
                        HPs[r0 * 520 + col] = f2bf(c0[r]);
                        const int r1 = 16 + quad * 4 + r;
                        if (r1 < NPG) HPs[r1 * 520 + col] = f2bf(c1[r]);
                    }
                }
            }
            __syncthreads();
            const int e = wm * 16 + li;
            const int i1 = p ? tl[e] : fl[e];
            const int i2 = p ? fl[e] : tl[e];
            const int ad1 = i1 * 520 + quad * 8;
            const int ad2 = i2 * 520 + 256 + quad * 8;
            const int ade = p * 16384 + e * 32 + quad * 8;
            const ushort* W2L = p ? W2rL : W2fL;
            const ushort* pb[4];
#pragma unroll
            for (int ni = 0; ni < 4; ++ni)
                pb[ni] = W2L + (size_t)(n0 + ni * 16 + li) * 32 + quad * 8;
#pragma unroll
            for (int kb = 0; kb < 8; ++kb) {
                const uint4 u1 = *(const uint4*)&HPs[ad1 + kb * 32];
                const uint4 u2 = *(const uint4*)&HPs[ad2 + kb * 32];
                const uint4 ue = *(const uint4*)&ECs[ade + kb * 2048];
                uint4 o;
                o.x = relu_sum_pk(u1.x, u2.x, ue.x);
                o.y = relu_sum_pk(u1.y, u2.y, ue.y);
                o.z = relu_sum_pk(u1.z, u2.z, ue.z);
                o.w = relu_sum_pk(u1.w, u2.w, ue.w);
                const bf16x8 a = __builtin_bit_cast(bf16x8, o);
#pragma unroll
                for (int ni = 0; ni < 4; ++ni) {
                    const bf16x8 b = __builtin_bit_cast(bf16x8,
                        *(const uint4*)(pb[ni] + (size_t)kb * 4096));
                    acc[ni] = mfma16(a, b, acc[ni]);
                }
            }
            __syncthreads();
        }
        float bv[4];
#pragma unroll
        for (int ni = 0; ni < 4; ++ni)
            bv[ni] = b2f[n0 + ni * 16 + li] + b2r[n0 + ni * 16 + li];
#pragma unroll
        for (int r = 0; r < 4; ++r) {
            const int erow = g * 64 + wm * 16 + quad * 4 + r;
#pragma unroll
            for (int ni = 0; ni < 4; ++ni)
                EM[(size_t)erow * 128 + n0 + ni * 16 + li] = acc[ni][r] + bv[ni];
        }
    }
    for (int u = tid; u < NPG * 128; u += 512)
        h[(size_t)g * (NPG * 128) + u] = hs[(u >> 7) * 132 + (u & 127)];
}

// ---------------------------------------------------------------------------
// Weight packing (verified round-12)
// ---------------------------------------------------------------------------
__global__ __launch_bounds__(256) void pack2(
    const float* __restrict__ msg_w1, const float* __restrict__ rmsg_w1,
    const float* __restrict__ msg_b1, const float* __restrict__ rmsg_b1,
    const float* __restrict__ enc_ew, const float* __restrict__ enc_eb,
    const float* __restrict__ enc_nw,
    const float* __restrict__ msg_w2, const float* __restrict__ rmsg_w2,
    const float* __restrict__ upd_w1, const float* __restrict__ upd_w2,
    ushort* __restrict__ WcombL, float* __restrict__ bcomb,
    ushort* __restrict__ encL,
    ushort* __restrict__ WhpL, ushort* __restrict__ W2fL, ushort* __restrict__ W2rL,
    ushort* __restrict__ UW1T, ushort* __restrict__ UW2T)
{
    const int gid = blockIdx.x, tid = threadIdx.x;
    if (gid < 64) {
        const int idx = gid * 256 + tid;
        const int a = idx >> 9, n = idx & 511;
        const float* Wsrc = (n < 256) ? msg_w1 : rmsg_w1;
        const int nc = n & 255;
        float s = 0.f;
        for (int j = 0; j < 128; ++j)
            s = fmaf(enc_ew[a * 128 + j], Wsrc[(256 + j) * 256 + nc], s);
        WcombL[n * 32 + a] = f2bf(s);
    } else if (gid < 66) {
        const int n = (gid - 64) * 256 + tid;
        const float* Wsrc = (n < 256) ? msg_w1 : rmsg_w1;
        const float* bsrc = (n < 256) ? msg_b1 : rmsg_b1;
        const int nc = n & 255;
        float s = bsrc[nc];
        for (int j = 0; j < 128; ++j)
            s = fmaf(enc_eb[j], Wsrc[(256 + j) * 256 + nc], s);
        bcomb[n] = s;
    } else if (gid < 82) {
        const int idx = (gid - 66) * 256 + tid;
        const int n = idx >> 5, k = idx & 31;
        encL[idx] = f2bf(enc_nw[k * 128 + n]);
    } else if (gid < 594) {
        const int idx = (gid - 82) * 256 + tid;
        const int n = idx >> 7, k = idx & 127;
        const float* Wsrc = (n < 512) ? msg_w1 : rmsg_w1;
        const int part = (n >> 8) & 1, col = n & 255;
        WhpL[(size_t)(k >> 5) * 32768 + n * 32 + (k & 31)] =
            f2bf(Wsrc[(part * 128 + k) * 256 + col]);
    } else if (gid < 722) {
        const int idx = (gid - 594) * 256 + tid;
        const int n = idx >> 8, k = idx & 255;
        W2fL[(size_t)(k >> 5) * 4096 + n * 32 + (k & 31)] = f2bf(msg_w2[k * 128 + n]);
    } else if (gid < 850) {
        const int idx = (gid - 722) * 256 + tid;
        const int n = idx >> 8, k = idx & 255;
        W2rL[(size_t)(k >> 5) * 4096 + n * 32 + (k & 31)] = f2bf(rmsg_w2[k * 128 + n]);
    } else if (gid < 1106) {
        const int idx = (gid - 850) * 256 + tid;
        const int n = idx >> 8, k = idx & 255;
        UW1T[idx] = f2bf(upd_w1[k * 256 + n]);
    } else {
        const int idx = (gid - 1106) * 256 + tid;
        const int n = idx >> 8, k = idx & 255;
        UW2T[idx] = f2bf(upd_w2[k * 128 + n]);
    }
}

// ---------------------------------------------------------------------------
// Fused heads, 512 threads, LDS-aliased phases (<= ~64 KB -> 2 blocks/CU).
// Phase N (node): pool = qn/cn/t1/mq/mc. Phase E (edge): pool = ce/la64/idx.
// la32 (plan) persists across phases; plan never touches HBM.
// All phase internals are the verified round-20 versions.
// ---------------------------------------------------------------------------
__global__ __launch_bounds__(512) void heads_fused(
    const float* __restrict__ h, const float* __restrict__ EM,
    const float* __restrict__ w1, const float* __restrict__ b1,
    const float* __restrict__ w2, const float* __restrict__ b2,
    const int* __restrict__ qsz, const int* __restrict__ csz,
    const int* __restrict__ from_idx, const int* __restrict__ to_idx,
    float* __restrict__ loss_out)
{
    __shared__ float la32[32][33];
    __shared__ float red[8];
    __shared__ float nodeloss_s;
    __shared__ float pool[14848];   // 59.4 KB aliased region

    float (*qn)[132] = (float(*)[132])pool;            // 32 x 132
    float (*cn)[132] = (float(*)[132])(pool + 4224);   // 32 x 132
    float (*t1)[64]  = (float(*)[64]) (pool + 8448);   // 32 x 64
    float (*mq)[68]  = (float(*)[68]) (pool + 10496);  // 32 x 68
    float (*mc)[68]  = (float(*)[68]) (pool + 12672);  // 32 x 68
    // edge-phase aliases (valid after node align completes)
    float (*ce)[132]  = (float(*)[132])pool;           // 64 x 132
    float (*la64)[65] = (float(*)[65])(pool + 8448);   // 64 x 65
    int* qf  = (int*)(pool + 12608);
    int* qt  = qf + 64;
    int* cfi = qt + 64;
    int* cti = cfi + 64;

    const int bb = blockIdx.x;
    const int tid = threadIdx.x;
    const int qs = qsz[bb], cs = csz[bb];

    // ---- phase N: stage node features
    for (int u = tid * 4; u < 4096; u += 2048) {
        const int p = u >> 7, d = u & 127;
        float4 zq = make_float4(0.f, 0.f, 0.f, 0.f), zc = zq;
        if (p < NPG) {
            zq = *(const float4*)(h + (size_t)((2 * bb) * NPG + p) * 128 + d);
            zc = *(const float4*)(h + (size_t)((2 * bb + 1) * NPG + p) * 128 + d);
        }
        *(float4*)&qn[p][d] = zq;
        *(float4*)&cn[p][d] = zc;
    }
    __syncthreads();
    // sk-MLP (512 threads)
    const int col = tid & 63;
    const int rg  = tid >> 6;
    for (int s = 0; s < 2; ++s) {
        const float (*src)[132] = s ? cn : qn;
        float (*dst)[68] = s ? mc : mq;
        const int sz = s ? cs : qs;
        float a4[4];
#pragma unroll
        for (int u = 0; u < 4; ++u) a4[u] = b1[col];
        for (int k = 0; k < 128; ++k) {
            const float wv = w1[k * 64 + col];
#pragma unroll
            for (int u = 0; u < 4; ++u) a4[u] = fmaf(src[rg + 8 * u][k], wv, a4[u]);
        }
#pragma unroll
        for (int u = 0; u < 4; ++u) t1[rg + 8 * u][col] = fmaxf(a4[u], 0.f);
        __syncthreads();
#pragma unroll
        for (int u = 0; u < 4; ++u) a4[u] = b2[col];
        for (int k = 0; k < 64; ++k) {
            const float wv = w2[k * 64 + col];
#pragma unroll
            for (int u = 0; u < 4; ++u) a4[u] = fmaf(t1[rg + 8 * u][k], wv, a4[u]);
        }
#pragma unroll
        for (int u = 0; u < 4; ++u) {
            const int r = rg + 8 * u;
            dst[r][col] = (r < sz) ? a4[u] : 0.f;
        }
        __syncthreads();
    }
    {   // node scores
        const int q = tid >> 4, cg = tid & 15;
#pragma unroll
        for (int u = 0; u < 2; ++u) {
            const int c = cg + 16 * u;
            float s = 0.f;
            for (int d = 0; d < 64; ++d) s = fmaf(mq[q][d], mc[c][d], s);
            la32[q][c] = s * TEMPINV;
        }
    }
    __syncthreads();
    // node Sinkhorn (verified 256-thread mapping; waves 4..7 idle)
    if (tid < 256) {
        const int l8 = tid & 7, rq = tid >> 3;
        for (int it = 0; it < SINK_ITERS; ++it) {
            {
                float x[4];
#pragma unroll
                for (int u = 0; u < 4; ++u) x[u] = la32[rq][l8 * 4 + u];
                float m = fmaxf(fmaxf(x[0], x[1]), fmaxf(x[2], x[3]));
                m = fmaxf(m, __shfl_xor(m, 1));
                m = fmaxf(m, __shfl_xor(m, 2));
                m = fmaxf(m, __shfl_xor(m, 4));
                float s = __expf(x[0] - m) + __expf(x[1] - m) + __expf(x[2] - m) + __expf(x[3] - m);
                s += __shfl_xor(s, 1);
                s += __shfl_xor(s, 2);
                s += __shfl_xor(s, 4);
                const float lse = m + __logf(s);
#pragma unroll
                for (int u = 0; u < 4; ++u) la32[rq][l8 * 4 + u] = x[u] - lse;
            }
            __builtin_amdgcn_s_barrier();
            {
                float x[4];
#pragma unroll
                for (int u = 0; u < 4; ++u) x[u] = la32[l8 * 4 + u][rq];
                float m = fmaxf(fmaxf(x[0], x[1]), fmaxf(x[2], x[3]));
                m = fmaxf(m, __shfl_xor(m, 1));
                m = fmaxf(m, __shfl_xor(m, 2));
                m = fmaxf(m, __shfl_xor(m, 4));
                float s = __expf(x[0] - m) + __expf(x[1] - m) + __expf(x[2] - m) + __expf(x[3] - m);
                s += __shfl_xor(s, 1);
                s += __shfl_xor(s, 2);
                s += __shfl_xor(s, 4);
                const float lse = m + __logf(s);
#pragma unroll
                for (int u = 0; u < 4; ++u) la32[l8 * 4 + u][rq] = x[u] - lse;
            }
            __builtin_amdgcn_s_barrier();
        }
    } else {
        for (int it = 0; it < SINK_ITERS * 2; ++it) __builtin_amdgcn_s_barrier();
    }
    __syncthreads();
    for (int u = tid; u < 1024; u += 512) {
        const int q = u >> 5, c = u & 31;
        la32[q][c] = __expf(la32[q][c]);
    }
    __syncthreads();
    float lsum = 0.f;
    {   // node align (c-outer, float4 cn reads)
        const int q = tid >> 4, dg = tid & 15;
        float pc[8];
#pragma unroll
        for (int u = 0; u < 8; ++u) pc[u] = 0.f;
        for (int c = 0; c < 32; ++c) {
            const float p = la32[q][c];
            const float* rowc = &cn[c][dg * 8];
#pragma unroll
            for (int v = 0; v < 2; ++v) {
                const float4 cv = *(const float4*)(rowc + 4 * v);
                pc[4 * v + 0] = fmaf(p, cv.x, pc[4 * v + 0]);
                pc[4 * v + 1] = fmaf(p, cv.y, pc[4 * v + 1]);
                pc[4 * v + 2] = fmaf(p, cv.z, pc[4 * v + 2]);
                pc[4 * v + 3] = fmaf(p, cv.w, pc[4 * v + 3]);
            }
        }
        const float* qrow = &qn[q][dg * 8];
#pragma unroll
        for (int u = 0; u < 8; ++u)
            lsum += fmaxf(qrow[u] - pc[u], 0.f);
    }
#pragma unroll
    for (int off = 1; off < 64; off <<= 1) lsum += __shfl_xor(lsum, off);
    if ((tid & 63) == 0) red[tid >> 6] = lsum;
    __syncthreads();
    if (tid == 0) {
        float t = 0.f;
#pragma unroll
        for (int i = 0; i < 8; ++i) t += red[i];
        nodeloss_s = t;
    }
    __syncthreads();   // node phase fully done; pool is now reusable

    // ---- phase E: stage ce + edge indices (aliases over node pool)
    {
        const int gc = 2 * bb + 1;
        for (int u = tid * 4; u < 8192; u += 2048) {
            const int i = u >> 7, d = u & 127;
            *(float4*)&ce[i][d] = *(const float4*)(EM + (size_t)(gc * 64 + i) * 128 + d);
        }
    }
    if (tid < 64) {
        const int gq = 2 * bb, gc = 2 * bb + 1;
        qf[tid]  = from_idx[gq * 64 + tid] - gq * NPG;
        qt[tid]  = to_idx  [gq * 64 + tid] - gq * NPG;
        cfi[tid] = from_idx[gc * 64 + tid] - gc * NPG;
        cti[tid] = to_idx  [gc * 64 + tid] - gc * NPG;
    }
    __syncthreads();
    {   // edge scores (kron of node plan in la32)
        const int i = tid >> 3, jg = tid & 7;
        const int a = qf[i], b_ = qt[i];
#pragma unroll
        for (int u = 0; u < 8; ++u) {
            const int j = jg * 8 + u;
            const float s = la32[a][cfi[j]] * la32[b_][cti[j]] +
                            la32[a][cti[j]] * la32[b_][cfi[j]];
            la64[i][j] = s * TEMPINV;
        }
    }
    __syncthreads();
    if (tid < 256) {
        const int l4 = tid & 3, rr = tid >> 2;
        for (int it = 0; it < SINK_ITERS; ++it) {
            {
                float x[16];
#pragma unroll
                for (int u = 0; u < 16; ++u) x[u] = la64[rr][l4 * 16 + u];
                float m = x[0];
#pragma unroll
                for (int u = 1; u < 16; ++u) m = fmaxf(m, x[u]);
                m = fmaxf(m, __shfl_xor(m, 1));
                m = fmaxf(m, __shfl_xor(m, 2));
                float s = 0.f;
#pragma unroll
                for (int u = 0; u < 16; ++u) s += __expf(x[u] - m);
                s += __shfl_xor(s, 1);
                s += __shfl_xor(s, 2);
                const float lse = m + __logf(s);
#pragma unroll
                for (int u = 0; u < 16; ++u) la64[rr][l4 * 16 + u] = x[u] - lse;
            }
            __builtin_amdgcn_s_barrier();
            {
                float x[16];
#pragma unroll
                for (int u = 0; u < 16; ++u) x[u] = la64[l4 * 16 + u][rr];
                float m = x[0];
#pragma unroll
                for (int u = 1; u < 16; ++u) m = fmaxf(m, x[u]);
                m = fmaxf(m, __shfl_xor(m, 1));
                m = fmaxf(m, __shfl_xor(m, 2));
                float s = 0.f;
#pragma unroll
                for (int u = 0; u < 16; ++u) s += __expf(x[u] - m);
                s += __shfl_xor(s, 1);
                s += __shfl_xor(s, 2);
                const float lse = m + __logf(s);
#pragma unroll
                for (int u = 0; u < 16; ++u) la64[l4 * 16 + u][rr] = x[u] - lse;
            }
            __builtin_amdgcn_s_barrier();
        }
    } else {
        for (int it = 0; it < SINK_ITERS * 2; ++it) __builtin_amdgcn_s_barrier();
    }
    __syncthreads();
    for (int u = tid; u < 4096; u += 512) la64[u >> 6][u & 63] = __expf(la64[u >> 6][u & 63]);
    __syncthreads();
    lsum = 0.f;
    {   // edge align (c-outer, float4 ce reads)
        const int q = tid >> 3, dg = tid & 7;
        float pc[16];
#pragma unroll
        for (int u = 0; u < 16; ++u) pc[u] = 0.f;
        for (int c = 0; c < 64; ++c) {
            const float p = la64[q][c];
            const float* rowc = &ce[c][dg * 16];
#pragma unroll
            for (int v = 0; v < 4; ++v) {
                const float4 cv = *(const float4*)(rowc + 4 * v);
                pc[4 * v + 0] = fmaf(p, cv.x, pc[4 * v + 0]);
                pc[4 * v + 1] = fmaf(p, cv.y, pc[4 * v + 1]);
                pc[4 * v + 2] = fmaf(p, cv.z, pc[4 * v + 2]);
                pc[4 * v + 3] = fmaf(p, cv.w, pc[4 * v + 3]);
            }
        }
        const float* qe = EM + (size_t)((2 * bb) * 64 + q) * 128 + dg * 16;
#pragma unroll
        for (int u = 0; u < 16; ++u)
            lsum += fmaxf(qe[u] - pc[u], 0.f);
    }
#pragma unroll
    for (int off = 1; off < 64; off <<= 1) lsum += __shfl_xor(lsum, off);
    if ((tid & 63) == 0) red[tid >> 6] = lsum;
    __syncthreads();
    if (tid == 0) {
        float t = 0.f;
#pragma unroll
        for (int i = 0; i < 8; ++i) t += red[i];
        loss_out[bb] = -nodeloss_s - CW * t;
    }
}

// ---------------------------------------------------------------------------
extern "C" void kernel_launch(void* const* d_in, const int* in_sizes, int n_in,
                              void* d_out, int out_size, void* d_ws, size_t ws_size,
                              hipStream_t stream)
{
    const float* node_features = (const float*)d_in[0];
    const float* edge_features = (const float*)d_in[1];
    const float* enc_nw  = (const float*)d_in[2];
    const float* enc_nb  = (const float*)d_in[3];
    const float* enc_ew  = (const float*)d_in[4];
    const float* enc_eb  = (const float*)d_in[5];
    const float* msg_w1  = (const float*)d_in[6];
    const float* msg_b1  = (const float*)d_in[7];
    const float* msg_w2  = (const float*)d_in[8];
    const float* msg_b2  = (const float*)d_in[9];
    const float* rmsg_w1 = (const float*)d_in[10];
    const float* rmsg_b1 = (const float*)d_in[11];
    const float* rmsg_w2 = (const float*)d_in[12];
    const float* rmsg_b2 = (const float*)d_in[13];
    const float* upd_w1  = (const float*)d_in[14];
    const float* upd_b1  = (const float*)d_in[15];
    const float* upd_w2  = (const float*)d_in[16];
    const float* upd_b2  = (const float*)d_in[17];
    const float* sk_w1   = (const float*)d_in[18];
    const float* sk_b1   = (const float*)d_in[19];
    const float* sk_w2   = (const float*)d_in[20];
    const float* sk_b2   = (const float*)d_in[21];
    const int* from_idx  = (const int*)d_in[22];
    const int* to_idx    = (const int*)d_in[23];
    const int* qsizes    = (const int*)d_in[24];
    const int* csizes    = (const int*)d_in[25];
    float* out = (float*)d_out;

    float* ws     = (float*)d_ws;
    float* h      = ws;                         // NN*128 fp32
    float* EM     = h + (size_t)NN * 128;       // NE*128 fp32
    float* bcomb  = EM + (size_t)NE * 128;      // 512
    ushort* WcombL = (ushort*)(bcomb + 512);    // 512*32
    ushort* encL  = WcombL + 16384;             // 128*32
    ushort* WhpL  = encL + 4096;                // 131072
    ushort* W2fL  = WhpL + 131072;              // 32768
    ushort* W2rL  = W2fL + 32768;               // 32768
    ushort* UW1T  = W2rL + 32768;               // 65536
    ushort* UW2T  = UW1T + 65536;               // 32768

    const dim3 blk(256);
    const dim3 blk512(512);

    pack2<<<1234, blk, 0, stream>>>(msg_w1, rmsg_w1, msg_b1, rmsg_b1,
                                    enc_ew, enc_eb, enc_nw, msg_w2, rmsg_w2,
                                    upd_w1, upd_w2,
                                    WcombL, bcomb, encL, WhpL, W2fL, W2rL, UW1T, UW2T);

    gnn_fused<<<dim3(NG), blk512, 0, stream>>>(
        node_features, edge_features, encL, enc_nb, WcombL, bcomb,
        WhpL, W2fL, W2rL, msg_b2, rmsg_b2,
        UW1T, upd_b1, UW2T, upd_b2, from_idx, to_idx, h, EM);

    heads_fused<<<NB, blk512, 0, stream>>>(
        h, EM, sk_w1, sk_b1, sk_w2, sk_b2, qsizes, csizes,
        from_idx, to_idx, out);
}

// Round 22
// 449.061 us; speedup vs baseline: 1.0585x; 1.0585x over previous
//
#include <hip/hip_runtime.h>
#include <math.h>

#define NPG 28
#define EPG 64
#define NB  256
#define NG  512
#define NN  14336
#define NE  32768
#define TEMPINV 10.0f
#define SINK_ITERS 20
#define CW 0.9f

typedef unsigned int uint;
typedef unsigned short ushort;
typedef __attribute__((ext_vector_type(8))) __bf16 bf16x8;
typedef __attribute__((ext_vector_type(4))) float f32x4;

__device__ __forceinline__ ushort f2bf(float x) {
    uint u = __float_as_uint(x);
    u += 0x7fffu + ((u >> 16) & 1u);
    return (ushort)(u >> 16);
}
__device__ __forceinline__ uint f2bf2(float lo, float hi) {
    return (uint)f2bf(lo) | ((uint)f2bf(hi) << 16);
}
__device__ __forceinline__ float bflo(uint w) { return __uint_as_float(w << 16); }
__device__ __forceinline__ float bfhi(uint w) { return __uint_as_float(w & 0xffff0000u); }
__device__ __forceinline__ uint relu_sum_pk(uint w1, uint w2, uint w3) {
    float lo = fmaxf(bflo(w1) + bflo(w2) + bflo(w3), 0.f);
    float hi = fmaxf(bfhi(w1) + bfhi(w2) + bfhi(w3), 0.f);
    return f2bf2(lo, hi);
}
__device__ __forceinline__ uint4 pack_f32x8(const float* src) {
    const float4 f0 = *(const float4*)src;
    const float4 f1 = *(const float4*)(src + 4);
    uint4 o;
    o.x = f2bf2(f0.x, f0.y);
    o.y = f2bf2(f0.z, f0.w);
    o.z = f2bf2(f1.x, f1.y);
    o.w = f2bf2(f1.z, f1.w);
    return o;
}
__device__ __forceinline__ f32x4 mfma16(bf16x8 a, bf16x8 b, f32x4 c) {
    return __builtin_amdgcn_mfma_f32_16x16x32_bf16(a, b, c, 0, 0, 0);
}

// ---------------------------------------------------------------------------
// Mega-fused GNN kernel (round-12/14 verified structure, UNCHANGED)
// ---------------------------------------------------------------------------
__global__ __launch_bounds__(512) void gnn_fused(
    const float* __restrict__ nf, const float* __restrict__ ef,
    const ushort* __restrict__ encL, const float* __restrict__ enc_nb,
    const ushort* __restrict__ WcombL, const float* __restrict__ bcomb,
    const ushort* __restrict__ WhpL,
    const ushort* __restrict__ W2fL, const ushort* __restrict__ W2rL,
    const float* __restrict__ b2f, const float* __restrict__ b2r,
    const ushort* __restrict__ UW1T, const float* __restrict__ ub1,
    const ushort* __restrict__ UW2T, const float* __restrict__ ub2,
    const int* __restrict__ from_idx, const int* __restrict__ to_idx,
    float* __restrict__ h, float* __restrict__ EM)
{
    __shared__ ushort HPs[NPG * 520];
    __shared__ ushort ECs[2 * 8 * 2048];
    __shared__ float acc_s[NPG * 132];
    __shared__ float hs[NPG * 132];
    __shared__ int fl[64], tl[64];
    const int g = blockIdx.x;
    const int tid = threadIdx.x;
    const int w = tid >> 6, lane = tid & 63;
    const int li = lane & 15, quad = lane >> 4;
    const int wm = w >> 1, wn = w & 1;
    ushort* hid = &HPs[0];

    if (tid < 64) {
        fl[tid] = from_idx[g * 64 + tid] - g * NPG;
        tl[tid] = to_idx[g * 64 + tid] - g * NPG;
    }

    {   // node encoder
        uint4 anf[2];
#pragma unroll
        for (int mi = 0; mi < 2; ++mi) {
            const int row = mi * 16 + li;
            const int rr = (row < NPG) ? row : 0;
            const float4 f0 = *(const float4*)(nf + ((size_t)g * NPG + rr) * 32 + quad * 8);
            const float4 f1 = *(const float4*)(nf + ((size_t)g * NPG + rr) * 32 + quad * 8 + 4);
            uint4 o;
            o.x = f2bf2(f0.x, f0.y); o.y = f2bf2(f0.z, f0.w);
            o.z = f2bf2(f1.x, f1.y); o.w = f2bf2(f1.z, f1.w);
            anf[mi] = o;
        }
        const int col = w * 16 + li;
        const bf16x8 b = __builtin_bit_cast(bf16x8,
            *(const uint4*)(encL + (size_t)col * 32 + quad * 8));
        f32x4 c0 = mfma16(__builtin_bit_cast(bf16x8, anf[0]), b, f32x4{0.f, 0.f, 0.f, 0.f});
        f32x4 c1 = mfma16(__builtin_bit_cast(bf16x8, anf[1]), b, f32x4{0.f, 0.f, 0.f, 0.f});
        const float bv = enc_nb[col];
#pragma unroll
        for (int r = 0; r < 4; ++r) {
            const int r0 = quad * 4 + r;
            hs[r0 * 132 + col] = c0[r] + bv;
            const int r1 = 16 + quad * 4 + r;
            if (r1 < NPG) hs[r1 * 132 + col] = c1[r] + bv;
        }
    }
    {   // EC in LDS
        uint4 aef[4];
#pragma unroll
        for (int mi = 0; mi < 4; ++mi) {
            const int e = mi * 16 + li;
            const float4 f0 = *(const float4*)(ef + ((size_t)g * 64 + e) * 32 + quad * 8);
            const float4 f1 = *(const float4*)(ef + ((size_t)g * 64 + e) * 32 + quad * 8 + 4);
            uint4 o;
            o.x = f2bf2(f0.x, f0.y); o.y = f2bf2(f0.z, f0.w);
            o.z = f2bf2(f1.x, f1.y); o.w = f2bf2(f1.z, f1.w);
            aef[mi] = o;
        }
#pragma unroll
        for (int ni = 0; ni < 4; ++ni) {
            const int col = w * 64 + ni * 16 + li;
            const bf16x8 b = __builtin_bit_cast(bf16x8,
                *(const uint4*)(WcombL + (size_t)col * 32 + quad * 8));
            const float bv = bcomb[col];
            const int pp = col >> 8, kbl = (col >> 5) & 7, j = col & 31;
#pragma unroll
            for (int mi = 0; mi < 4; ++mi) {
                f32x4 c = mfma16(__builtin_bit_cast(bf16x8, aef[mi]), b,
                                 f32x4{0.f, 0.f, 0.f, 0.f});
#pragma unroll
                for (int r = 0; r < 4; ++r) {
                    const int e = mi * 16 + quad * 4 + r;
                    ECs[pp * 16384 + kbl * 2048 + e * 32 + j] = f2bf(c[r] + bv);
                }
            }
        }
    }
    __syncthreads();

#pragma unroll 1
    for (int step = 0; step < 3; ++step) {
        uint4 ha[2][4];
#pragma unroll
        for (int mi = 0; mi < 2; ++mi) {
            const int row = mi * 16 + li;
            const int rr = (row < NPG) ? row : 0;
#pragma unroll
            for (int kb = 0; kb < 4; ++kb)
                ha[mi][kb] = pack_f32x8(&hs[rr * 132 + kb * 32 + quad * 8]);
        }
        for (int u = tid; u < NPG * 132; u += 512) acc_s[u] = 0.f;

        f32x4 acc[4];
#pragma unroll
        for (int j = 0; j < 4; ++j) acc[j] = f32x4{0.f, 0.f, 0.f, 0.f};

#pragma unroll 1
        for (int p = 0; p < 2; ++p) {
            {
                const int colw = w * 64;
#pragma unroll
                for (int ni = 0; ni < 4; ++ni) {
                    const int col = colw + ni * 16 + li;
                    const ushort* pb = WhpL + (size_t)(p * 512 + col) * 32 + quad * 8;
                    f32x4 c0 = f32x4{0.f, 0.f, 0.f, 0.f};
                    f32x4 c1 = f32x4{0.f, 0.f, 0.f, 0.f};
#pragma unroll
                    for (int kb = 0; kb < 4; ++kb) {
                        const bf16x8 b = __builtin_bit_cast(bf16x8,
                            *(const uint4*)(pb + (size_t)kb * 32768));
                        c0 = mfma16(__builtin_bit_cast(bf16x8, ha[0][kb]), b, c0);
                        c1 = mfma16(__builtin_bit_cast(bf16x8, ha[1][kb]), b, c1);
                    }
#pragma unroll
                    for (int r = 0; r < 4; ++r) {
                        const int r0 = quad * 4 + r;
                        HPs[r0 * 520 + col] = f2bf(c0[r]);
                        const int r1 = 16 + quad * 4 + r;
                        if (r1 < NPG) HPs[r1 * 520 + col] = f2bf(c1[r]);
                    }
                }
            }
            __syncthreads();

            if (p == 1) {
#pragma unroll
                for (int j = 0; j < 4; ++j) acc[j] = f32x4{0.f, 0.f, 0.f, 0.f};
            }
            const int e = wm * 16 + li;
            const int i1 = p ? tl[e] : fl[e];
            const int i2 = p ? fl[e] : tl[e];
            const int ad1 = i1 * 520 + quad * 8;
            const int ad2 = i2 * 520 + 256 + quad * 8;
            const int ade = p * 16384 + e * 32 + quad * 8;
            const ushort* W2L = p ? W2rL : W2fL;
            const int n0 = wn * 64;
            const ushort* pb[4];
#pragma unroll
            for (int ni = 0; ni < 4; ++ni)
                pb[ni] = W2L + (size_t)(n0 + ni * 16 + li) * 32 + quad * 8;
#pragma unroll
            for (int kb = 0; kb < 8; ++kb) {
                const uint4 u1 = *(const uint4*)&HPs[ad1 + kb * 32];
                const uint4 u2 = *(const uint4*)&HPs[ad2 + kb * 32];
                const uint4 ue = *(const uint4*)&ECs[ade + kb * 2048];
                uint4 o;
                o.x = relu_sum_pk(u1.x, u2.x, ue.x);
                o.y = relu_sum_pk(u1.y, u2.y, ue.y);
                o.z = relu_sum_pk(u1.z, u2.z, ue.z);
                o.w = relu_sum_pk(u1.w, u2.w, ue.w);
                const bf16x8 a = __builtin_bit_cast(bf16x8, o);
#pragma unroll
                for (int ni = 0; ni < 4; ++ni) {
                    const bf16x8 b = __builtin_bit_cast(bf16x8,
                        *(const uint4*)(pb[ni] + (size_t)kb * 4096));
                    acc[ni] = mfma16(a, b, acc[ni]);
                }
            }
            {
                const int* targ = p ? fl : tl;
                const float* bias = p ? b2r : b2f;
                float bv[4];
#pragma unroll
                for (int ni = 0; ni < 4; ++ni) bv[ni] = bias[n0 + ni * 16 + li];
#pragma unroll
                for (int r = 0; r < 4; ++r) {
                    const int loc = targ[wm * 16 + quad * 4 + r];
#pragma unroll
                    for (int ni = 0; ni < 4; ++ni)
                        atomicAdd(&acc_s[loc * 132 + n0 + ni * 16 + li],
                                  acc[ni][r] + bv[ni]);
                }
            }
            __syncthreads();
        }

        {   // upd1
            const int n0u = w * 32;
            f32x4 ua[2][2];
#pragma unroll
            for (int mi = 0; mi < 2; ++mi)
#pragma unroll
                for (int ni = 0; ni < 2; ++ni) ua[mi][ni] = f32x4{0.f, 0.f, 0.f, 0.f};
            const ushort* pb0 = UW1T + (size_t)(n0u + li) * 256 + quad * 8;
            const ushort* pb1 = UW1T + (size_t)(n0u + 16 + li) * 256 + quad * 8;
#pragma unroll
            for (int kb = 0; kb < 8; ++kb) {
                bf16x8 a[2];
                if (kb < 4) {
#pragma unroll
                    for (int mi = 0; mi < 2; ++mi) {
                        const int row = mi * 16 + li;
                        const int rr = (row < NPG) ? row : 0;
                        a[mi] = __builtin_bit_cast(bf16x8,
                            pack_f32x8(&acc_s[rr * 132 + kb * 32 + quad * 8]));
                    }
                } else {
                    a[0] = __builtin_bit_cast(bf16x8, ha[0][kb - 4]);
                    a[1] = __builtin_bit_cast(bf16x8, ha[1][kb - 4]);
                }
                const bf16x8 b0 = __builtin_bit_cast(bf16x8, *(const uint4*)(pb0 + kb * 32));
                const bf16x8 b1 = __builtin_bit_cast(bf16x8, *(const uint4*)(pb1 + kb * 32));
#pragma unroll
                for (int mi = 0; mi < 2; ++mi) {
                    ua[mi][0] = mfma16(a[mi], b0, ua[mi][0]);
                    ua[mi][1] = mfma16(a[mi], b1, ua[mi][1]);
                }
            }
            const float bv0 = ub1[n0u + li], bv1 = ub1[n0u + 16 + li];
#pragma unroll
            for (int mi = 0; mi < 2; ++mi)
#pragma unroll
                for (int r = 0; r < 4; ++r) {
                    const int row = mi * 16 + quad * 4 + r;
                    if (row < NPG) {
                        hid[row * 264 + n0u + li] = f2bf(fmaxf(ua[mi][0][r] + bv0, 0.f));
                        hid[row * 264 + n0u + 16 + li] = f2bf(fmaxf(ua[mi][1][r] + bv1, 0.f));
                    }
                }
        }
        __syncthreads();
        {   // upd2
            const int n0u = w * 16;
            f32x4 ua[2];
            ua[0] = f32x4{0.f, 0.f, 0.f, 0.f};
            ua[1] = f32x4{0.f, 0.f, 0.f, 0.f};
            const ushort* pb0 = UW2T + (size_t)(n0u + li) * 256 + quad * 8;
#pragma unroll
            for (int kb = 0; kb < 8; ++kb) {
                bf16x8 a[2];
#pragma unroll
                for (int mi = 0; mi < 2; ++mi) {
                    const int row = mi * 16 + li;
                    const int rr = (row < NPG) ? row : 0;
                    a[mi] = __builtin_bit_cast(bf16x8,
                        *(const uint4*)&hid[rr * 264 + kb * 32 + quad * 8]);
                }
                const bf16x8 b0 = __builtin_bit_cast(bf16x8, *(const uint4*)(pb0 + kb * 32));
                ua[0] = mfma16(a[0], b0, ua[0]);
                ua[1] = mfma16(a[1], b0, ua[1]);
            }
            const float bv = ub2[n0u + li];
#pragma unroll
            for (int mi = 0; mi < 2; ++mi)
#pragma unroll
                for (int r = 0; r < 4; ++r) {
                    const int row = mi * 16 + quad * 4 + r;
                    if (row < NPG)
                        hs[row * 132 + n0u + li] += ua[mi][r] + bv;
                }
        }
        __syncthreads();
    }

    // final messages (EMIT)
    {
        uint4 ha[2][4];
#pragma unroll
        for (int mi = 0; mi < 2; ++mi) {
            const int row = mi * 16 + li;
            const int rr = (row < NPG) ? row : 0;
#pragma unroll
            for (int kb = 0; kb < 4; ++kb)
                ha[mi][kb] = pack_f32x8(&hs[rr * 132 + kb * 32 + quad * 8]);
        }
        f32x4 acc[4];
#pragma unroll
        for (int j = 0; j < 4; ++j) acc[j] = f32x4{0.f, 0.f, 0.f, 0.f};
        const int n0 = wn * 64;
#pragma unroll 1
        for (int p = 0; p < 2; ++p) {
            {
                const int colw = w * 64;
#pragma unroll
                for (int ni = 0; ni < 4; ++ni) {
                    const int col = colw + ni * 16 + li;
                    const ushort* pb = WhpL + (size_t)(p * 512 + col) * 32 + quad * 8;
                    f32x4 c0 = f32x4{0.f, 0.f, 0.f, 0.f};
                    f32x4 c1 = f32x4{0.f, 0.f, 0.f, 0.f};
#pragma unroll
                    for (int kb = 0; kb < 4; ++kb) {
                        const bf16x8 b = __builtin_bit_cast(bf16x8,
                            *(const uint4*)(pb + (size_t)kb * 32768));
                        c0 = mfma16(__builtin_bit_cast(bf16x8, ha[0][kb]), b, c0);
                        c1 = mfma16(__builtin_bit_cast(bf16x8, ha[1][kb]), b, c1);
                    }
#pragma unroll
                    for (int r = 0; r < 4; ++r) {
                        const int r0 = quad * 4 + r;
                        HPs[r0 * 520 + col] = f2bf(c0[r]);
                        const int r1 = 16 + quad * 4 + r;
                        if (r1 < NPG) HPs[r1 * 520 + col] = f2bf(c1[r]);
                    }
                }
            }
            __syncthreads();
            const int e = wm * 16 + li;
            const int i1 = p ? tl[e] : fl[e];
            const int i2 = p ? fl[e] : tl[e];
            const int ad1 = i1 * 520 + quad * 8;
            const int ad2 = i2 * 520 + 256 + quad * 8;
            const int ade = p * 16384 + e * 32 + quad * 8;
            const ushort* W2L = p ? W2rL : W2fL;
            const ushort* pb[4];
#pragma unroll
            for (int ni = 0; ni < 4; ++ni)
                pb[ni] = W2L + (size_t)(n0 + ni * 16 + li) * 32 + quad * 8;
#pragma unroll
            for (int kb = 0; kb < 8; ++kb) {
                const uint4 u1 = *(const uint4*)&HPs[ad1 + kb * 32];
                const uint4 u2 = *(const uint4*)&HPs[ad2 + kb * 32];
                const uint4 ue = *(const uint4*)&ECs[ade + kb * 2048];
                uint4 o;
                o.x = relu_sum_pk(u1.x, u2.x, ue.x);
                o.y = relu_sum_pk(u1.y, u2.y, ue.y);
                o.z = relu_sum_pk(u1.z, u2.z, ue.z);
                o.w = relu_sum_pk(u1.w, u2.w, ue.w);
                const bf16x8 a = __builtin_bit_cast(bf16x8, o);
#pragma unroll
                for (int ni = 0; ni < 4; ++ni) {
                    const bf16x8 b = __builtin_bit_cast(bf16x8,
                        *(const uint4*)(pb[ni] + (size_t)kb * 4096));
                    acc[ni] = mfma16(a, b, acc[ni]);
                }
            }
            __syncthreads();
        }
        float bv[4];
#pragma unroll
        for (int ni = 0; ni < 4; ++ni)
            bv[ni] = b2f[n0 + ni * 16 + li] + b2r[n0 + ni * 16 + li];
#pragma unroll
        for (int r = 0; r < 4; ++r) {
            const int erow = g * 64 + wm * 16 + quad * 4 + r;
#pragma unroll
            for (int ni = 0; ni < 4; ++ni)
                EM[(size_t)erow * 128 + n0 + ni * 16 + li] = acc[ni][r] + bv[ni];
        }
    }
    for (int u = tid; u < NPG * 128; u += 512)
        h[(size_t)g * (NPG * 128) + u] = hs[(u >> 7) * 132 + (u & 127)];
}

// ---------------------------------------------------------------------------
// Weight packing (verified round-12)
// ---------------------------------------------------------------------------
__global__ __launch_bounds__(256) void pack2(
    const float* __restrict__ msg_w1, const float* __restrict__ rmsg_w1,
    const float* __restrict__ msg_b1, const float* __restrict__ rmsg_b1,
    const float* __restrict__ enc_ew, const float* __restrict__ enc_eb,
    const float* __restrict__ enc_nw,
    const float* __restrict__ msg_w2, const float* __restrict__ rmsg_w2,
    const float* __restrict__ upd_w1, const float* __restrict__ upd_w2,
    ushort* __restrict__ WcombL, float* __restrict__ bcomb,
    ushort* __restrict__ encL,
    ushort* __restrict__ WhpL, ushort* __restrict__ W2fL, ushort* __restrict__ W2rL,
    ushort* __restrict__ UW1T, ushort* __restrict__ UW2T)
{
    const int gid = blockIdx.x, tid = threadIdx.x;
    if (gid < 64) {
        const int idx = gid * 256 + tid;
        const int a = idx >> 9, n = idx & 511;
        const float* Wsrc = (n < 256) ? msg_w1 : rmsg_w1;
        const int nc = n & 255;
        float s = 0.f;
        for (int j = 0; j < 128; ++j)
            s = fmaf(enc_ew[a * 128 + j], Wsrc[(256 + j) * 256 + nc], s);
        WcombL[n * 32 + a] = f2bf(s);
    } else if (gid < 66) {
        const int n = (gid - 64) * 256 + tid;
        const float* Wsrc = (n < 256) ? msg_w1 : rmsg_w1;
        const float* bsrc = (n < 256) ? msg_b1 : rmsg_b1;
        const int nc = n & 255;
        float s = bsrc[nc];
        for (int j = 0; j < 128; ++j)
            s = fmaf(enc_eb[j], Wsrc[(256 + j) * 256 + nc], s);
        bcomb[n] = s;
    } else if (gid < 82) {
        const int idx = (gid - 66) * 256 + tid;
        const int n = idx >> 5, k = idx & 31;
        encL[idx] = f2bf(enc_nw[k * 128 + n]);
    } else if (gid < 594) {
        const int idx = (gid - 82) * 256 + tid;
        const int n = idx >> 7, k = idx & 127;
        const float* Wsrc = (n < 512) ? msg_w1 : rmsg_w1;
        const int part = (n >> 8) & 1, col = n & 255;
        WhpL[(size_t)(k >> 5) * 32768 + n * 32 + (k & 31)] =
            f2bf(Wsrc[(part * 128 + k) * 256 + col]);
    } else if (gid < 722) {
        const int idx = (gid - 594) * 256 + tid;
        const int n = idx >> 8, k = idx & 255;
        W2fL[(size_t)(k >> 5) * 4096 + n * 32 + (k & 31)] = f2bf(msg_w2[k * 128 + n]);
    } else if (gid < 850) {
        const int idx = (gid - 722) * 256 + tid;
        const int n = idx >> 8, k = idx & 255;
        W2rL[(size_t)(k >> 5) * 4096 + n * 32 + (k & 31)] = f2bf(rmsg_w2[k * 128 + n]);
    } else if (gid < 1106) {
        const int idx = (gid - 850) * 256 + tid;
        const int n = idx >> 8, k = idx & 255;
        UW1T[idx] = f2bf(upd_w1[k * 256 + n]);
    } else {
        const int idx = (gid - 1106) * 256 + tid;
        const int n = idx >> 8, k = idx & 255;
        UW2T[idx] = f2bf(upd_w2[k * 128 + n]);
    }
}

// ---------------------------------------------------------------------------
// Node head: 512 threads (verified round-20)
// ---------------------------------------------------------------------------
__global__ __launch_bounds__(512) void node_kernel(
    const float* __restrict__ h,
    const float* __restrict__ w1, const float* __restrict__ b1,
    const float* __restrict__ w2, const float* __restrict__ b2,
    const int* __restrict__ qsz, const int* __restrict__ csz,
    float* __restrict__ plan_out, float* __restrict__ loss_out)
{
    __shared__ float qn[32][132];
    __shared__ float cn[32][132];
    __shared__ float t1[32][64];
    __shared__ float mq[32][68];
    __shared__ float mc[32][68];
    __shared__ float la[32][33];
    __shared__ float red[8];
    const int bb = blockIdx.x;
    const int tid = threadIdx.x;
    const int qs = qsz[bb], cs = csz[bb];
    for (int u = tid * 4; u < 4096; u += 2048) {
        const int p = u >> 7, d = u & 127;
        float4 zq = make_float4(0.f, 0.f, 0.f, 0.f), zc = zq;
        if (p < NPG) {
            zq = *(const float4*)(h + (size_t)((2 * bb) * NPG + p) * 128 + d);
            zc = *(const float4*)(h + (size_t)((2 * bb + 1) * NPG + p) * 128 + d);
        }
        *(float4*)&qn[p][d] = zq;
        *(float4*)&cn[p][d] = zc;
    }
    __syncthreads();
    const int col = tid & 63;
    const int rg  = tid >> 6;
    for (int s = 0; s < 2; ++s) {
        const float (*src)[132] = s ? cn : qn;
        float (*dst)[68] = s ? mc : mq;
        const int sz = s ? cs : qs;
        float a4[4];
#pragma unroll
        for (int u = 0; u < 4; ++u) a4[u] = b1[col];
        for (int k = 0; k < 128; ++k) {
            const float wv = w1[k * 64 + col];
#pragma unroll
            for (int u = 0; u < 4; ++u) a4[u] = fmaf(src[rg + 8 * u][k], wv, a4[u]);
        }
#pragma unroll
        for (int u = 0; u < 4; ++u) t1[rg + 8 * u][col] = fmaxf(a4[u], 0.f);
        __syncthreads();
#pragma unroll
        for (int u = 0; u < 4; ++u) a4[u] = b2[col];
        for (int k = 0; k < 64; ++k) {
            const float wv = w2[k * 64 + col];
#pragma unroll
            for (int u = 0; u < 4; ++u) a4[u] = fmaf(t1[rg + 8 * u][k], wv, a4[u]);
        }
#pragma unroll
        for (int u = 0; u < 4; ++u) {
            const int r = rg + 8 * u;
            dst[r][col] = (r < sz) ? a4[u] : 0.f;
        }
        __syncthreads();
    }
    {
        const int q = tid >> 4, cg = tid & 15;
#pragma unroll
        for (int u = 0; u < 2; ++u) {
            const int c = cg + 16 * u;
            float s = 0.f;
            for (int d = 0; d < 64; ++d) s = fmaf(mq[q][d], mc[c][d], s);
            la[q][c] = s * TEMPINV;
        }
    }
    __syncthreads();
    if (tid < 256) {
        const int l8 = tid & 7, rq = tid >> 3;
        for (int it = 0; it < SINK_ITERS; ++it) {
            {
                float x[4];
#pragma unroll
                for (int u = 0; u < 4; ++u) x[u] = la[rq][l8 * 4 + u];
                float m = fmaxf(fmaxf(x[0], x[1]), fmaxf(x[2], x[3]));
                m = fmaxf(m, __shfl_xor(m, 1));
                m = fmaxf(m, __shfl_xor(m, 2));
                m = fmaxf(m, __shfl_xor(m, 4));
                float s = __expf(x[0] - m) + __expf(x[1] - m) + __expf(x[2] - m) + __expf(x[3] - m);
                s += __shfl_xor(s, 1);
                s += __shfl_xor(s, 2);
                s += __shfl_xor(s, 4);
                const float lse = m + __logf(s);
#pragma unroll
                for (int u = 0; u < 4; ++u) la[rq][l8 * 4 + u] = x[u] - lse;
            }
            __builtin_amdgcn_s_barrier();
            {
                float x[4];
#pragma unroll
                for (int u = 0; u < 4; ++u) x[u] = la[l8 * 4 + u][rq];
                float m = fmaxf(fmaxf(x[0], x[1]), fmaxf(x[2], x[3]));
                m = fmaxf(m, __shfl_xor(m, 1));
                m = fmaxf(m, __shfl_xor(m, 2));
                m = fmaxf(m, __shfl_xor(m, 4));
                float s = __expf(x[0] - m) + __expf(x[1] - m) + __expf(x[2] - m) + __expf(x[3] - m);
                s += __shfl_xor(s, 1);
                s += __shfl_xor(s, 2);
                s += __shfl_xor(s, 4);
                const float lse = m + __logf(s);
#pragma unroll
                for (int u = 0; u < 4; ++u) la[l8 * 4 + u][rq] = x[u] - lse;
            }
            __builtin_amdgcn_s_barrier();
        }
    } else {
        for (int it = 0; it < SINK_ITERS * 2; ++it) __builtin_amdgcn_s_barrier();
    }
    __syncthreads();
    for (int u = tid; u < 1024; u += 512) {
        const int q = u >> 5, c = u & 31;
        const float p = __expf(la[q][c]);
        la[q][c] = p;
        plan_out[(size_t)bb * 1024 + u] = p;
    }
    __syncthreads();
    float lsum = 0.f;
    {
        const int q = tid >> 4, dg = tid & 15;
        float pc[8];
#pragma unroll
        for (int u = 0; u < 8; ++u) pc[u] = 0.f;
        for (int c = 0; c < 32; ++c) {
            const float p = la[q][c];
            const float* rowc = &cn[c][dg * 8];
#pragma unroll
            for (int v = 0; v < 2; ++v) {
                const float4 cv = *(const float4*)(rowc + 4 * v);
                pc[4 * v + 0] = fmaf(p, cv.x, pc[4 * v + 0]);
                pc[4 * v + 1] = fmaf(p, cv.y, pc[4 * v + 1]);
                pc[4 * v + 2] = fmaf(p, cv.z, pc[4 * v + 2]);
                pc[4 * v + 3] = fmaf(p, cv.w, pc[4 * v + 3]);
            }
        }
        const float* qrow = &qn[q][dg * 8];
#pragma unroll
        for (int u = 0; u < 8; ++u)
            lsum += fmaxf(qrow[u] - pc[u], 0.f);
    }
#pragma unroll
    for (int off = 1; off < 64; off <<= 1) lsum += __shfl_xor(lsum, off);
    if ((tid & 63) == 0) red[tid >> 6] = lsum;
    __syncthreads();
    if (tid == 0) {
        float t = 0.f;
#pragma unroll
        for (int i = 0; i < 8; ++i) t += red[i];
        loss_out[bb] = -t;
    }
}

// ---------------------------------------------------------------------------
// Edge head: 512 threads (verified round-20)
// ---------------------------------------------------------------------------
__global__ __launch_bounds__(512) void edge_kernel(
    const float* __restrict__ plan, const float* __restrict__ EM,
    const int* __restrict__ from_idx, const int* __restrict__ to_idx,
    float* __restrict__ loss_out)
{
    __shared__ float T[32][33];
    __shared__ float la[64][65];
    __shared__ float ce[64][132];
    __shared__ int qf[64], qt[64], cfi[64], cti[64];
    __shared__ float red[8];
    const int bb = blockIdx.x;
    const int tid = threadIdx.x;
    for (int u = tid; u < 1024; u += 512) T[u >> 5][u & 31] = plan[(size_t)bb * 1024 + u];
    if (tid < 64) {
        const int gq = 2 * bb, gc = 2 * bb + 1;
        qf[tid]  = from_idx[gq * 64 + tid] - gq * NPG;
        qt[tid]  = to_idx  [gq * 64 + tid] - gq * NPG;
        cfi[tid] = from_idx[gc * 64 + tid] - gc * NPG;
        cti[tid] = to_idx  [gc * 64 + tid] - gc * NPG;
    }
    {
        const int gc = 2 * bb + 1;
        for (int u = tid * 4; u < 8192; u += 2048) {
            const int i = u >> 7, d = u & 127;
            *(float4*)&ce[i][d] = *(const float4*)(EM + (size_t)(gc * 64 + i) * 128 + d);
        }
    }
    __syncthreads();
    {
        const int i = tid >> 3, jg = tid & 7;
        const int a = qf[i], b_ = qt[i];
#pragma unroll
        for (int u = 0; u < 8; ++u) {
            const int j = jg * 8 + u;
            const float s = T[a][cfi[j]] * T[b_][cti[j]] + T[a][cti[j]] * T[b_][cfi[j]];
            la[i][j] = s * TEMPINV;
        }
    }
    __syncthreads();
    if (tid < 256) {
        const int l4 = tid & 3, rr = tid >> 2;
        for (int it = 0; it < SINK_ITERS; ++it) {
            {
                float x[16];
#pragma unroll
                for (int u = 0; u < 16; ++u) x[u] = la[rr][l4 * 16 + u];
                float m = x[0];
#pragma unroll
                for (int u = 1; u < 16; ++u) m = fmaxf(m, x[u]);
                m = fmaxf(m, __shfl_xor(m, 1));
                m = fmaxf(m, __shfl_xor(m, 2));
                float s = 0.f;
#pragma unroll
                for (int u = 0; u < 16; ++u) s += __expf(x[u] - m);
                s += __shfl_xor(s, 1);
                s += __shfl_xor(s, 2);
                const float lse = m + __logf(s);
#pragma unroll
                for (int u = 0; u < 16; ++u) la[rr][l4 * 16 + u] = x[u] - lse;
            }
            __builtin_amdgcn_s_barrier();
            {
                float x[16];
#pragma unroll
                for (int u = 0; u < 16; ++u) x[u] = la[l4 * 16 + u][rr];
                float m = x[0];
#pragma unroll
                for (int u = 1; u < 16; ++u) m = fmaxf(m, x[u]);
                m = fmaxf(m, __shfl_xor(m, 1));
                m = fmaxf(m, __shfl_xor(m, 2));
                float s = 0.f;
#pragma unroll
                for (int u = 0; u < 16; ++u) s += __expf(x[u] - m);
                s += __shfl_xor(s, 1);
                s += __shfl_xor(s, 2);
                const float lse = m + __logf(s);
#pragma unroll
                for (int u = 0; u < 16; ++u) la[l4 * 16 + u][rr] = x[u] - lse;
            }
            __builtin_amdgcn_s_barrier();
        }
    } else {
        for (int it = 0; it < SINK_ITERS * 2; ++it) __builtin_amdgcn_s_barrier();
    }
    __syncthreads();
    for (int u = tid; u < 4096; u += 512) la[u >> 6][u & 63] = __expf(la[u >> 6][u & 63]);
    __syncthreads();
    float lsum = 0.f;
    {
        const int q = tid >> 3, dg = tid & 7;
        float pc[16];
#pragma unroll
        for (int u = 0; u < 16; ++u) pc[u] = 0.f;
        for (int c = 0; c < 64; ++c) {
            const float p = la[q][c];
            const float* rowc = &ce[c][dg * 16];
#pragma unroll
            for (int v = 0; v < 4; ++v) {
                const float4 cv = *(const float4*)(rowc + 4 * v);
                pc[4 * v + 0] = fmaf(p, cv.x, pc[4 * v + 0]);
                pc[4 * v + 1] = fmaf(p, cv.y, pc[4 * v + 1]);
                pc[4 * v + 2] = fmaf(p, cv.z, pc[4 * v + 2]);
                pc[4 * v + 3] = fmaf(p, cv.w, pc[4 * v + 3]);
            }
        }
        const float* qe = EM + (size_t)((2 * bb) * 64 + q) * 128 + dg * 16;
#pragma unroll
        for (int u = 0; u < 16; ++u)
            lsum += fmaxf(qe[u] - pc[u], 0.f);
    }
#pragma unroll
    for (int off = 1; off < 64; off <<= 1) lsum += __shfl_xor(lsum, off);
    if ((tid & 63) == 0) red[tid >> 6] = lsum;
    __syncthreads();
    if (tid == 0) {
        float t = 0.f;
#pragma unroll
        for (int i = 0; i < 8; ++i) t += red[i];
        loss_out[bb] -= CW * t;
    }
}

// ---------------------------------------------------------------------------
extern "C" void kernel_launch(void* const* d_in, const int* in_sizes, int n_in,
                              void* d_out, int out_size, void* d_ws, size_t ws_size,
                              hipStream_t stream)
{
    const float* node_features = (const float*)d_in[0];
    const float* edge_features = (const float*)d_in[1];
    const float* enc_nw  = (const float*)d_in[2];
    const float* enc_nb  = (const float*)d_in[3];
    const float* enc_ew  = (const float*)d_in[4];
    const float* enc_eb  = (const float*)d_in[5];
    const float* msg_w1  = (const float*)d_in[6];
    const float* msg_b1  = (const float*)d_in[7];
    const float* msg_w2  = (const float*)d_in[8];
    const float* msg_b2  = (const float*)d_in[9];
    const float* rmsg_w1 = (const float*)d_in[10];
    const float* rmsg_b1 = (const float*)d_in[11];
    const float* rmsg_w2 = (const float*)d_in[12];
    const float* rmsg_b2 = (const float*)d_in[13];
    const float* upd_w1  = (const float*)d_in[14];
    const float* upd_b1  = (const float*)d_in[15];
    const float* upd_w2  = (const float*)d_in[16];
    const float* upd_b2  = (const float*)d_in[17];
    const float* sk_w1   = (const float*)d_in[18];
    const float* sk_b1   = (const float*)d_in[19];
    const float* sk_w2   = (const float*)d_in[20];
    const float* sk_b2   = (const float*)d_in[21];
    const int* from_idx  = (const int*)d_in[22];
    const int* to_idx    = (const int*)d_in[23];
    const int* qsizes    = (const int*)d_in[24];
    const int* csizes    = (const int*)d_in[25];
    float* out = (float*)d_out;

    float* ws     = (float*)d_ws;
    float* h      = ws;                         // NN*128 fp32
    float* EM     = h + (size_t)NN * 128;       // NE*128 fp32
    float* plan   = EM + (size_t)NE * 128;      // NB*1024
    float* bcomb  = plan + (size_t)NB * 1024;   // 512
    ushort* WcombL = (ushort*)(bcomb + 512);    // 512*32
    ushort* encL  = WcombL + 16384;             // 128*32
    ushort* WhpL  = encL + 4096;                // 131072
    ushort* W2fL  = WhpL + 131072;              // 32768
    ushort* W2rL  = W2fL + 32768;               // 32768
    ushort* UW1T  = W2rL + 32768;               // 65536
    ushort* UW2T  = UW1T + 65536;               // 32768

    const dim3 blk(256);
    const dim3 blk512(512);

    pack2<<<1234, blk, 0, stream>>>(msg_w1, rmsg_w1, msg_b1, rmsg_b1,
                                    enc_ew, enc_eb, enc_nw, msg_w2, rmsg_w2,
                                    upd_w1, upd_w2,
                                    WcombL, bcomb, encL, WhpL, W2fL, W2rL, UW1T, UW2T);

    gnn_fused<<<dim3(NG), blk512, 0, stream>>>(
        node_features, edge_features, encL, enc_nb, WcombL, bcomb,
        WhpL, W2fL, W2rL, msg_b2, rmsg_b2,
        UW1T, upd_b1, UW2T, upd_b2, from_idx, to_idx, h, EM);

    node_kernel<<<NB, blk512, 0, stream>>>(
        h, sk_w1, sk_b1, sk_w2, sk_b2, qsizes, csizes, plan, out);
    edge_kernel<<<NB, blk512, 0, stream>>>(
        plan, EM, from_idx, to_idx, out);
}